// Round 15
// baseline (164.158 us; speedup 1.0000x reference)
//
#include <hip/hip_runtime.h>
#include <hip/hip_bf16.h>

// ---------- helpers ----------
__device__ __forceinline__ float bits2f(unsigned int b) {
    union { unsigned int u; float f; } v; v.u = b; return v.f;
}
__device__ __forceinline__ unsigned short f2bf_bits(float f) {
    union { float f; unsigned int u; } v; v.f = f;
    return (unsigned short)((v.u + 0x7fffu + ((v.u >> 16) & 1u)) >> 16);
}
__device__ __forceinline__ unsigned short f2h_bits(_Float16 h) {
    union { _Float16 f; unsigned short u; } v; v.f = h; return v.u;
}

typedef __attribute__((ext_vector_type(8))) short short8;
typedef __attribute__((ext_vector_type(4))) float f32x4;
typedef _Float16 f16x8 __attribute__((ext_vector_type(8)));

// lane r gets lane r-1's value (width-16 groups); r==0 gets carry's lane-15
__device__ __forceinline__ f16x8 shuf_prev16(f16x8 cur, f16x8 carry, int lane) {
    union U { f16x8 h; int u[4]; } a, c, o;
    a.h = cur; c.h = carry;
    const int src15 = (lane & 48) | 15;
    const bool isr0 = (lane & 15) == 0;
    #pragma unroll
    for (int k = 0; k < 4; ++k) {
        int up  = __shfl_up(a.u[k], 1, 16);
        int c15 = __shfl(c.u[k], src15, 64);
        o.u[k] = isr0 ? c15 : up;
    }
    return o.h;
}

#define AS1 __attribute__((address_space(1)))
#define AS3 __attribute__((address_space(3)))

// prep-built tables (rewritten every launch: deterministic)
__device__ __align__(16) unsigned short g_muwb[512 * 512];
__device__ __align__(16) unsigned short g_dec1B[4096];   // [p][tap][o][i] bf16
__device__ __align__(16) unsigned short g_dec2B[5120];   // [j(16)][k(320)] bf16
__device__ __align__(16) unsigned short g_encBh[4096];   // [j][o][i] f16 hi
__device__ __align__(16) unsigned short g_encBl[4096];   // [j][o][i] f16 lo*2048
__device__ float g_cc[512];                              // codebook row norms
__device__ __align__(16) float g_cbT[64 * 512];          // codebook^T [d][c]
__device__ __align__(16) float g_embwT[164 * 64];        // embw^T [k][j]

// =====================================================================
// Prep: mu_w->bf16; decoder B-tables; enc-L1 f16-split B; cc norms;
// codebook^T and embw^T for coalesced tail access
// =====================================================================
__global__ __launch_bounds__(256)
void k_prep(const float* __restrict__ muw, const float* __restrict__ dw1,
            const float* __restrict__ dw2, const float* __restrict__ ew1,
            const float* __restrict__ cb, const float* __restrict__ embw)
{
    int idx = blockIdx.x * 256 + threadIdx.x;
    if (idx < 262144) { g_muwb[idx] = f2bf_bits(muw[idx]); return; }
    int e = idx - 262144;
    if (e < 4096) {
        const int jsel[4] = {1, 3, 2, 0};
        int pt = e >> 10, o = (e >> 5) & 31, i = e & 31;
        g_dec1B[e] = f2bf_bits(dw1[i * 128 + o * 4 + jsel[pt]]);
        return;
    }
    int f = e - 4096;
    if (f < 5120) {
        int j = f / 320, k = f - j * 320;
        int lam = k >> 5, i = k & 31, q = j >> 1;
        float v = 0.f;
        if ((j & 1) == 0) {
            if (lam == q + 1) v = dw2[4 * i + 1];
            else if (lam == q) v = dw2[4 * i + 3];
        } else {
            if (lam == q + 1) v = dw2[4 * i + 2];
            else if (lam == q + 2) v = dw2[4 * i + 0];
        }
        g_dec2B[f] = f2bf_bits(v);
        return;
    }
    int g = f - 5120;
    if (g < 4096) {
        // g = j*1024 + o*32 + i ; w1 flat [o][i][j]
        int j = g >> 10, o = (g >> 5) & 31, i = g & 31;
        float w = ew1[o * 128 + i * 4 + j];
        _Float16 wh = (_Float16)w;
        _Float16 wl = (_Float16)((w - (float)wh) * 2048.0f);
        g_encBh[g] = f2h_bits(wh);
        g_encBl[g] = f2h_bits(wl);
        return;
    }
    int h = g - 4096;
    if (h < 512) {
        const float4* cp = (const float4*)(cb + (size_t)h * 64);
        float cc2 = 0.f;
        #pragma unroll
        for (int q = 0; q < 16; ++q) {
            float4 u = cp[q];
            cc2 += u.x * u.x + u.y * u.y + u.z * u.z + u.w * u.w;
        }
        g_cc[h] = cc2;
        return;
    }
    int m = h - 512;
    if (m < 32768) {                       // cbT[d][c] = cb[c][d]
        int d = m >> 9, c = m & 511;
        g_cbT[m] = cb[(size_t)c * 64 + d];
        return;
    }
    int n2 = m - 32768;
    if (n2 < 10496) {                      // embwT[k][j] = embw[j][k]
        int k = n2 >> 6, j = n2 & 63;
        g_embwT[n2] = embw[(size_t)j * 164 + k];
    }
}

// =====================================================================
// Kernel E-front: encoder x -> z. TWO WAVES PER ROW, m-halved, with
// SHUFFLE-REUSE of the overlapping conv window: lane r's A-frags
// j0/j1 (t = 2t2-1, 2t2) are bitwise-identical to lane r-1's j2/j3
// (window-shift identity), so tiles mi>=1 compute only v2/v3 and
// derive ah0/al0/ah1/al1 via __shfl_up (r==0 takes prev tile's lane-15
// carry). Tile mi==0 computes all four directly (carry seed; covers
// the cross-wave boundary). Saves ~2x8x10 VALU ops per tile.
// =====================================================================
__global__ __launch_bounds__(256, 2)
void k_encoder(const float* __restrict__ x,
               const float* __restrict__ ew0, const float* __restrict__ eb0,
               const float* __restrict__ eb1,
               const float* __restrict__ ew2, const float* __restrict__ eb2,
               float* __restrict__ z_out)
{
    const int tid  = threadIdx.x;
    const int lane = tid & 63;
    const int w    = tid >> 6;                 // wave 0..3
    const int rloc = w >> 1;                   // row-in-block 0..1
    const int wh   = w & 1;                    // m-half 0/1
    const int row  = blockIdx.x * 2 + rloc;    // 0..8191

    __shared__ __align__(16) float POOL[2 * 4688];
    float* ws = POOL + rloc * 4688;
    float* xs = ws;                            // data at +3
    float* h2 = ws + 520;                      // rows ch*130, data +4

    const int r = lane & 15, kc = lane >> 4;
    const float biaN0 = eb1[r], biaN1 = eb1[16 + r];
    const f16x8 Z8 = {(_Float16)0.f, (_Float16)0.f, (_Float16)0.f, (_Float16)0.f,
                      (_Float16)0.f, (_Float16)0.f, (_Float16)0.f, (_Float16)0.f};

    // ---- stage x: each wave stages its half of the row (coalesced) ----
    const float* xrow = x + (size_t)row * 512;
    #pragma unroll
    for (int q = 0; q < 4; ++q) {
        const int ch = wh * 4 + q;
        xs[3 + lane + 64 * ch] = xrow[lane + 64 * ch];
    }
    if (wh == 0) {
        if (lane < 3) xs[lane] = 0.f;
        // h2 guards gi = 0..63 (rows 0..31 at +2/+3)
        h2[(lane >> 1) * 130 + 2 + (lane & 1)] = 0.f;
    } else {
        if (lane < 3) xs[515 + lane] = 0.f;
        if (lane < 2) { int gi = 64 + lane; h2[(gi >> 1) * 130 + 2 + (gi & 1)] = 0.f; }
    }

    // ---- B-fragments: m-independent, load once per wave ----
    f16x8 Bh[2][4], Bl[2][4];
    #pragma unroll
    for (int nt = 0; nt < 2; ++nt)
        #pragma unroll
        for (int j = 0; j < 4; ++j) {
            const int off = (j * 32 + nt * 16 + r) * 32 + kc * 8;
            Bh[nt][j] = *(const f16x8*)(g_encBh + off);
            Bl[nt][j] = *(const f16x8*)(g_encBl + off);
        }
    // ---- L0 weights: hoisted once per lane ----
    float4 Wv[8]; float b0v[8];
    #pragma unroll
    for (int i = 0; i < 8; ++i) {
        Wv[i]  = *(const float4*)(ew0 + (kc * 8 + i) * 4);
        b0v[i] = eb0[kc * 8 + i];
    }
    __syncthreads();

    f16x8 c2h, c2l, c3h, c3l;                  // carries (prev tile's j2/j3)

    // ---- mi = 0: full direct conv (carry seed / boundary) ----
    {
        const int m = 4 * wh;
        const int t2 = m * 16 + r;
        float xw[10];
        {
            const float* xwin = xs + 4 * t2;
            #pragma unroll
            for (int q = 0; q < 10; ++q) xw[q] = xwin[q];
        }
        f16x8 ah0, ah1, ah2, ah3, al0, al1, al2, al3;
        #pragma unroll
        for (int i = 0; i < 8; ++i) {
            const float4 W = Wv[i];
            const float b0 = b0v[i];
            float v0 = fmaxf(b0 + xw[0] * W.x + xw[1] * W.y + xw[2] * W.z + xw[3] * W.w, 0.f);
            float v1 = fmaxf(b0 + xw[2] * W.x + xw[3] * W.y + xw[4] * W.z + xw[5] * W.w, 0.f);
            float v2 = fmaxf(b0 + xw[4] * W.x + xw[5] * W.y + xw[6] * W.z + xw[7] * W.w, 0.f);
            float v3 = fmaxf(b0 + xw[6] * W.x + xw[7] * W.y + xw[8] * W.z + xw[9] * W.w, 0.f);
            _Float16 hh0 = (_Float16)v0, hh1 = (_Float16)v1;
            _Float16 hh2 = (_Float16)v2, hh3 = (_Float16)v3;
            _Float16 ll0 = (_Float16)((v0 - (float)hh0) * 2048.0f);
            _Float16 ll1 = (_Float16)((v1 - (float)hh1) * 2048.0f);
            _Float16 ll2 = (_Float16)((v2 - (float)hh2) * 2048.0f);
            _Float16 ll3 = (_Float16)((v3 - (float)hh3) * 2048.0f);
            ah0[i] = hh0; al0[i] = ll0;
            ah1[i] = hh1; al1[i] = ll1;
            ah2[i] = hh2; al2[i] = ll2;
            ah3[i] = hh3; al3[i] = ll3;
        }
        if (t2 == 0) { ah0 = Z8; al0 = Z8; }    // t = -1 guard (wh0 only)
        c2h = ah2; c2l = al2; c3h = ah3; c3l = al3;
        const int t0 = m * 16;
        #pragma unroll
        for (int nt = 0; nt < 2; ++nt) {
            f32x4 ahh = (f32x4){0.f, 0.f, 0.f, 0.f};
            f32x4 am  = (f32x4){0.f, 0.f, 0.f, 0.f};
            f32x4 all_= (f32x4){0.f, 0.f, 0.f, 0.f};
            ahh = __builtin_amdgcn_mfma_f32_16x16x32_f16(ah0, Bh[nt][0], ahh, 0, 0, 0);
            am  = __builtin_amdgcn_mfma_f32_16x16x32_f16(ah0, Bl[nt][0], am,  0, 0, 0);
            am  = __builtin_amdgcn_mfma_f32_16x16x32_f16(al0, Bh[nt][0], am,  0, 0, 0);
            all_= __builtin_amdgcn_mfma_f32_16x16x32_f16(al0, Bl[nt][0], all_,0, 0, 0);
            ahh = __builtin_amdgcn_mfma_f32_16x16x32_f16(ah1, Bh[nt][1], ahh, 0, 0, 0);
            am  = __builtin_amdgcn_mfma_f32_16x16x32_f16(ah1, Bl[nt][1], am,  0, 0, 0);
            am  = __builtin_amdgcn_mfma_f32_16x16x32_f16(al1, Bh[nt][1], am,  0, 0, 0);
            all_= __builtin_amdgcn_mfma_f32_16x16x32_f16(al1, Bl[nt][1], all_,0, 0, 0);
            ahh = __builtin_amdgcn_mfma_f32_16x16x32_f16(ah2, Bh[nt][2], ahh, 0, 0, 0);
            am  = __builtin_amdgcn_mfma_f32_16x16x32_f16(ah2, Bl[nt][2], am,  0, 0, 0);
            am  = __builtin_amdgcn_mfma_f32_16x16x32_f16(al2, Bh[nt][2], am,  0, 0, 0);
            all_= __builtin_amdgcn_mfma_f32_16x16x32_f16(al2, Bl[nt][2], all_,0, 0, 0);
            ahh = __builtin_amdgcn_mfma_f32_16x16x32_f16(ah3, Bh[nt][3], ahh, 0, 0, 0);
            am  = __builtin_amdgcn_mfma_f32_16x16x32_f16(ah3, Bl[nt][3], am,  0, 0, 0);
            am  = __builtin_amdgcn_mfma_f32_16x16x32_f16(al3, Bh[nt][3], am,  0, 0, 0);
            all_= __builtin_amdgcn_mfma_f32_16x16x32_f16(al3, Bl[nt][3], all_,0, 0, 0);
            const float bia = nt ? biaN1 : biaN0;
            float* orow = h2 + (nt * 16 + r) * 130 + 4 + t0 + kc * 4;
            #pragma unroll
            for (int e = 0; e < 4; ++e)
                orow[e] = fmaxf(ahh[e] + 4.8828125e-4f * am[e]
                                + 2.384185791015625e-07f * all_[e] + bia, 0.f);
        }
    }

    // ---- mi = 1..3: half conv + shuffle-reuse ----
    #pragma unroll
    for (int mi = 1; mi < 4; ++mi) {
        const int m = 4 * wh + mi;
        const int t2 = m * 16 + r;
        const float* xwin = xs + 4 * t2;
        const float x4 = xwin[4], x5 = xwin[5], x6 = xwin[6];
        const float x7 = xwin[7], x8 = xwin[8], x9 = xwin[9];
        f16x8 ah2, ah3, al2, al3;
        #pragma unroll
        for (int i = 0; i < 8; ++i) {
            const float4 W = Wv[i];
            const float b0 = b0v[i];
            float v2 = fmaxf(b0 + x4 * W.x + x5 * W.y + x6 * W.z + x7 * W.w, 0.f);
            float v3 = fmaxf(b0 + x6 * W.x + x7 * W.y + x8 * W.z + x9 * W.w, 0.f);
            _Float16 hh2 = (_Float16)v2, hh3 = (_Float16)v3;
            _Float16 ll2 = (_Float16)((v2 - (float)hh2) * 2048.0f);
            _Float16 ll3 = (_Float16)((v3 - (float)hh3) * 2048.0f);
            ah2[i] = hh2; al2[i] = ll2;
            ah3[i] = hh3; al3[i] = ll3;
        }
        f16x8 ah0 = shuf_prev16(ah2, c2h, lane);
        f16x8 al0 = shuf_prev16(al2, c2l, lane);
        f16x8 ah1 = shuf_prev16(ah3, c3h, lane);
        f16x8 al1 = shuf_prev16(al3, c3l, lane);
        c2h = ah2; c2l = al2; c3h = ah3; c3l = al3;
        if (t2 == 127) { ah3 = Z8; al3 = Z8; }  // t = 256 guard (wh1 mi3 r15)
        const int t0 = m * 16;
        #pragma unroll
        for (int nt = 0; nt < 2; ++nt) {
            f32x4 ahh = (f32x4){0.f, 0.f, 0.f, 0.f};
            f32x4 am  = (f32x4){0.f, 0.f, 0.f, 0.f};
            f32x4 all_= (f32x4){0.f, 0.f, 0.f, 0.f};
            ahh = __builtin_amdgcn_mfma_f32_16x16x32_f16(ah0, Bh[nt][0], ahh, 0, 0, 0);
            am  = __builtin_amdgcn_mfma_f32_16x16x32_f16(ah0, Bl[nt][0], am,  0, 0, 0);
            am  = __builtin_amdgcn_mfma_f32_16x16x32_f16(al0, Bh[nt][0], am,  0, 0, 0);
            all_= __builtin_amdgcn_mfma_f32_16x16x32_f16(al0, Bl[nt][0], all_,0, 0, 0);
            ahh = __builtin_amdgcn_mfma_f32_16x16x32_f16(ah1, Bh[nt][1], ahh, 0, 0, 0);
            am  = __builtin_amdgcn_mfma_f32_16x16x32_f16(ah1, Bl[nt][1], am,  0, 0, 0);
            am  = __builtin_amdgcn_mfma_f32_16x16x32_f16(al1, Bh[nt][1], am,  0, 0, 0);
            all_= __builtin_amdgcn_mfma_f32_16x16x32_f16(al1, Bl[nt][1], all_,0, 0, 0);
            ahh = __builtin_amdgcn_mfma_f32_16x16x32_f16(ah2, Bh[nt][2], ahh, 0, 0, 0);
            am  = __builtin_amdgcn_mfma_f32_16x16x32_f16(ah2, Bl[nt][2], am,  0, 0, 0);
            am  = __builtin_amdgcn_mfma_f32_16x16x32_f16(al2, Bh[nt][2], am,  0, 0, 0);
            all_= __builtin_amdgcn_mfma_f32_16x16x32_f16(al2, Bl[nt][2], all_,0, 0, 0);
            ahh = __builtin_amdgcn_mfma_f32_16x16x32_f16(ah3, Bh[nt][3], ahh, 0, 0, 0);
            am  = __builtin_amdgcn_mfma_f32_16x16x32_f16(ah3, Bl[nt][3], am,  0, 0, 0);
            am  = __builtin_amdgcn_mfma_f32_16x16x32_f16(al3, Bh[nt][3], am,  0, 0, 0);
            all_= __builtin_amdgcn_mfma_f32_16x16x32_f16(al3, Bl[nt][3], all_,0, 0, 0);
            const float bia = nt ? biaN1 : biaN0;
            float* orow = h2 + (nt * 16 + r) * 130 + 4 + t0 + kc * 4;
            #pragma unroll
            for (int e = 0; e < 4; ++e)
                orow[e] = fmaxf(ahh[e] + 4.8828125e-4f * am[e]
                                + 2.384185791015625e-07f * all_[e] + bia, 0.f);
        }
    }
    __syncthreads();

    // ---- L2: UNCHANGED, on wh=0 wave only; lane = t' -> bitwise z ----
    if (wh == 0) {
        const int t = lane;
        float pg[4];
        #pragma unroll
        for (int gg = 0; gg < 4; ++gg) {
            float p = 0.f;
            #pragma unroll
            for (int ii = 0; ii < 8; ++ii) {
                const int i = gg * 8 + ii;
                const float4 W = *(const float4*)(ew2 + i * 4);
                const float* hr = h2 + i * 130 + 4;
                p += hr[2 * t - 1] * W.x + hr[2 * t] * W.y
                   + hr[2 * t + 1] * W.z + hr[2 * t + 2] * W.w;
            }
            pg[gg] = p;
        }
        float zv = fmaxf(pg[0] + pg[1] + pg[2] + pg[3] + eb2[0], 0.f);
        z_out[(size_t)row * 64 + t] = zv;
    }
}

// =====================================================================
// Kernel E-tail: batched VQ + code + emb. 1024 blocks x 8 rows, 256 thr.
// (round-2 structure, unchanged)
// =====================================================================
__global__ __launch_bounds__(256)
void k_enc_tail(const float* __restrict__ z_in, const float* __restrict__ cb,
                const float* __restrict__ embb,
                const int* __restrict__ spk,
                float* __restrict__ code_out, float* __restrict__ din_g)
{
    const int blk  = blockIdx.x;          // 0..1023
    const int tid  = threadIdx.x;
    const int lane = tid & 63;
    const int wv   = tid >> 6;            // wave 0..3

    __shared__ __align__(16) float zs[8][64];
    __shared__ __align__(16) float csf[8][64];
    __shared__ float zzv[8];
    __shared__ float redv[4][8];
    __shared__ int   redi[4][8];
    __shared__ int   sidxs[8];

    const int jq = tid & 63;              // j / column index
    const int rq = tid >> 6;              // row group 0..3

    // ---- Phase A: load 8 z rows, coalesced ----
    #pragma unroll
    for (int ch = 0; ch < 2; ++ch) {
        const int rr = rq + ch * 4;
        zs[rr][jq] = z_in[((size_t)blk * 8 + rr) * 64 + jq];
    }
    __syncthreads();

    // ---- Phase B: zz butterfly emulation (threads 0..7, one row each) ----
    if (tid < 8) {
        float4 zr[16];
        #pragma unroll
        for (int q = 0; q < 16; ++q) zr[q] = *(const float4*)(&zs[tid][4 * q]);
        float u[32];
        #pragma unroll
        for (int q = 0; q < 8; ++q) {
            u[4 * q + 0] = __fadd_rn(__fmul_rn(zr[q].x, zr[q].x), __fmul_rn(zr[q + 8].x, zr[q + 8].x));
            u[4 * q + 1] = __fadd_rn(__fmul_rn(zr[q].y, zr[q].y), __fmul_rn(zr[q + 8].y, zr[q + 8].y));
            u[4 * q + 2] = __fadd_rn(__fmul_rn(zr[q].z, zr[q].z), __fmul_rn(zr[q + 8].z, zr[q + 8].z));
            u[4 * q + 3] = __fadd_rn(__fmul_rn(zr[q].w, zr[q].w), __fmul_rn(zr[q + 8].w, zr[q + 8].w));
        }
        #pragma unroll
        for (int off = 16; off; off >>= 1)
            #pragma unroll
            for (int i = 0; i < off; ++i) u[i] = __fadd_rn(u[i], u[i + off]);
        zzv[tid] = u[0];
    }

    // ---- Phase C: dot accumulation, codes c0=tid, c1=tid+256 ----
    float acc[8][2];
    #pragma unroll
    for (int r2 = 0; r2 < 8; ++r2) { acc[r2][0] = 0.f; acc[r2][1] = 0.f; }

    #pragma unroll 4
    for (int dq = 0; dq < 16; ++dq) {
        float4 zv[8];
        #pragma unroll
        for (int r2 = 0; r2 < 8; ++r2) zv[r2] = *(const float4*)(&zs[r2][4 * dq]);
        #pragma unroll
        for (int dd = 0; dd < 4; ++dd) {
            const int d = 4 * dq + dd;
            const float w0 = g_cbT[d * 512 + tid];
            const float w1 = g_cbT[d * 512 + 256 + tid];
            #pragma unroll
            for (int r2 = 0; r2 < 8; ++r2) {
                const float zd = (dd == 0) ? zv[r2].x : (dd == 1) ? zv[r2].y
                               : (dd == 2) ? zv[r2].z : zv[r2].w;
                acc[r2][0] = fmaf(w0, zd, acc[r2][0]);
                acc[r2][1] = fmaf(w1, zd, acc[r2][1]);
            }
        }
    }
    __syncthreads();     // zzv ready

    // ---- Phase D: dist + lexicographic argmin per row ----
    {
        const float cc0 = g_cc[tid], cc1 = g_cc[tid + 256];
        float best[8]; int bidx[8];
        #pragma unroll
        for (int r2 = 0; r2 < 8; ++r2) {
            const float zz = zzv[r2];
            float d0 = 0.5f * (zz - 2.f * acc[r2][0] + cc0);
            float d1 = 0.5f * (zz - 2.f * acc[r2][1] + cc1);
            best[r2] = d0; bidx[r2] = tid;
            if (d1 < best[r2]) { best[r2] = d1; bidx[r2] = tid + 256; }
        }
        #pragma unroll
        for (int off = 32; off; off >>= 1) {
            #pragma unroll
            for (int r2 = 0; r2 < 8; ++r2) {
                float od = __shfl_down(best[r2], off);
                int   oi = __shfl_down(bidx[r2], off);
                if (od < best[r2] || (od == best[r2] && oi < bidx[r2])) {
                    best[r2] = od; bidx[r2] = oi;
                }
            }
        }
        if (lane == 0) {
            #pragma unroll
            for (int r2 = 0; r2 < 8; ++r2) { redv[wv][r2] = best[r2]; redi[wv][r2] = bidx[r2]; }
        }
    }
    __syncthreads();
    if (tid < 8) {
        float bd = redv[0][tid]; int bi = redi[0][tid];
        #pragma unroll
        for (int w = 1; w < 4; ++w)
            if (redv[w][tid] < bd || (redv[w][tid] == bd && redi[w][tid] < bi)) {
                bd = redv[w][tid]; bi = redi[w][tid];
            }
        sidxs[tid] = min(max(bi, 0), 511);
    }
    __syncthreads();

    // ---- Phase E: code copy + embedding (coalesced via embwT) ----
    #pragma unroll
    for (int ch = 0; ch < 2; ++ch) {
        const int rr = rq + ch * 4;
        const int sx = sidxs[rr];
        const float cv = cb[(size_t)sx * 64 + jq];
        code_out[((size_t)blk * 8 + rr) * 64 + jq] = cv;   // bit-exact codebook row
        csf[rr][jq] = cv;
    }
    __syncthreads();
    #pragma unroll
    for (int ch = 0; ch < 2; ++ch) {
        const int rr = rq + ch * 4;
        const size_t b2 = (size_t)blk * 8 + rr;
        float pg[4];
        #pragma unroll
        for (int gg = 0; gg < 4; ++gg) {
            float p = 0.f;
            #pragma unroll
            for (int q = 0; q < 4; ++q) {
                const int k0 = 16 * gg + 4 * q;
                const float w0 = g_embwT[(k0 + 0) * 64 + jq];
                const float w1 = g_embwT[(k0 + 1) * 64 + jq];
                const float w2 = g_embwT[(k0 + 2) * 64 + jq];
                const float w3 = g_embwT[(k0 + 3) * 64 + jq];
                p += w0 * csf[rr][k0 + 0] + w1 * csf[rr][k0 + 1]
                   + w2 * csf[rr][k0 + 2] + w3 * csf[rr][k0 + 3];
            }
            pg[gg] = p;
        }
        float a = pg[0] + pg[1] + pg[2] + pg[3]
                + embb[jq] + g_embwT[(64 + spk[b2]) * 64 + jq];
        din_g[b2 * 64 + jq] = a;
    }
}

// =====================================================================
// Kernel D: decoder, WAVE-INDEPENDENT n-QUARTERS, ONE barrier.
// (round-13 structure, unchanged)
// =====================================================================
__global__ __launch_bounds__(256)
void k_decoder(const float* __restrict__ din_g,
               const float* __restrict__ dw0, const float* __restrict__ db0,
               const float* __restrict__ db1, const float* __restrict__ db2,
               unsigned short* __restrict__ hdec)
{
    const int gidx = blockIdx.x;            // 0..4095
    const int bblk = gidx >> 3;             // row group 0..511
    const int m0   = (gidx & 7) * 16;       // m0 step
    const int tid  = threadIdx.x;
    const int lane = tid & 63;
    const int q    = tid >> 6;              // wave = n-quarter 0..3

    __shared__ __align__(16) float        dins[16 * 68];
    __shared__ __align__(16) unsigned int d2c[4][10 * 16 * 18];   // per-wave

    // ---- cooperative dins load (unchanged expressions) ----
    {
        int b = tid >> 4, j4 = tid & 15;
        float4 v = *(const float4*)(din_g + ((size_t)bblk * 16 + b) * 64 + j4 * 4);
        float* dr = dins + b * 68 + 1 + j4 * 4;
        dr[0] = v.x; dr[1] = v.y; dr[2] = v.z; dr[3] = v.w;
        if (j4 == 0) { dins[b * 68] = 0.f; dins[b * 68 + 65] = 0.f; }
    }

    const int r = lane & 15, kc = lane >> 4;
    const float bia2 = db2[0];

    // ---- conv weights for this lane's 4 pairs pp = 4kc+j ----
    float4 Wa[4], Wb[4]; float ba0v[4], ba1v[4];
    #pragma unroll
    for (int j = 0; j < 4; ++j) {
        const int pp = 4 * kc + j;
        Wa[j] = *(const float4*)(dw0 + 8 * pp);
        Wb[j] = *(const float4*)(dw0 + 8 * pp + 4);
        ba0v[j] = db0[2 * pp];
        ba1v[j] = db0[2 * pp + 1];
    }
    // ---- phase2 B-fragments, both parities (static indexing) ----
    short8 B00[2], B10[2], B01[2], B11[2];
    #pragma unroll
    for (int p = 0; p < 2; ++p) {
        const unsigned short* Bp = g_dec1B + p * 2048;
        B00[p] = *(const short8*)(Bp + (r) * 32 + kc * 8);
        B10[p] = *(const short8*)(Bp + 1024 + (r) * 32 + kc * 8);
        B01[p] = *(const short8*)(Bp + (16 + r) * 32 + kc * 8);
        B11[p] = *(const short8*)(Bp + 1024 + (16 + r) * 32 + kc * 8);
    }
    const float bv0 = db1[r], bv1 = db1[16 + r];
    __syncthreads();                        // the ONLY barrier

    // ---- phase1: conv -> d1 in registers: d1r[tl][j], tau_global = 4q+tl ----
    unsigned int d1r[6][4];
    const float* dn = dins + r * 68 + 1;
    #pragma unroll
    for (int tl = 0; tl < 6; ++tl) {
        const int s = m0 - 1 + 4 * q + tl;
        const bool inb = (s >= 0 && s < 128);
        const int m = s >> 1;
        #pragma unroll
        for (int j = 0; j < 4; ++j) {
            unsigned int pk = 0u;
            if (inb) {
                float v0, v1;
                if (s & 1) { v0 = ba0v[j] + dn[m] * Wa[j].z + dn[m + 1] * Wa[j].x;
                             v1 = ba1v[j] + dn[m] * Wb[j].z + dn[m + 1] * Wb[j].x; }
                else       { v0 = ba0v[j] + dn[m] * Wa[j].y + dn[m - 1] * Wa[j].w;
                             v1 = ba1v[j] + dn[m] * Wb[j].y + dn[m - 1] * Wb[j].w; }
                pk = (unsigned int)f2bf_bits(fmaxf(v0, 0.f))
                   | ((unsigned int)f2bf_bits(fmaxf(v1, 0.f)) << 16);
            }
            d1r[tl][j] = pk;
        }
    }

    // ---- phase2: 10 slabs, fully unrolled; writes to PRIVATE d2c ----
    unsigned short* d2u = (unsigned short*)(d2c[q]);
    const int tb = 2 * m0 - 1 + 8 * q;
    #pragma unroll
    for (int sgl = 0; sgl < 10; ++sgl) {
        const int p     = 1 - (sgl & 1);            // compile-time
        const int tauAl = (sgl + 1) >> 1;           // compile-time
        const int tauBl = p ? tauAl + 1 : tauAl - 1;
        const int t = tb + sgl;
        if (t >= 0 && t < 256) {
            union { unsigned int u[4]; short8 s8; } am_, ap_;
            am_.u[0] = d1r[tauAl][0]; am_.u[1] = d1r[tauAl][1];
            am_.u[2] = d1r[tauAl][2]; am_.u[3] = d1r[tauAl][3];
            ap_.u[0] = d1r[tauBl][0]; ap_.u[1] = d1r[tauBl][1];
            ap_.u[2] = d1r[tauBl][2]; ap_.u[3] = d1r[tauBl][3];
            f32x4 acc0 = (f32x4){0.f, 0.f, 0.f, 0.f};
            f32x4 acc1 = (f32x4){0.f, 0.f, 0.f, 0.f};
            acc0 = __builtin_amdgcn_mfma_f32_16x16x32_bf16(am_.s8, B00[p], acc0, 0, 0, 0);
            acc0 = __builtin_amdgcn_mfma_f32_16x16x32_bf16(ap_.s8, B10[p], acc0, 0, 0, 0);
            acc1 = __builtin_amdgcn_mfma_f32_16x16x32_bf16(am_.s8, B01[p], acc1, 0, 0, 0);
            acc1 = __builtin_amdgcn_mfma_f32_16x16x32_bf16(ap_.s8, B11[p], acc1, 0, 0, 0);
            #pragma unroll
            for (int e = 0; e < 4; ++e) {
                int bC = kc * 4 + e;
                d2u[sgl * 576 + bC * 36 + r]      = f2bf_bits(fmaxf(acc0[e] + bv0, 0.f));
                d2u[sgl * 576 + bC * 36 + 16 + r] = f2bf_bits(fmaxf(acc1[e] + bv1, 0.f));
            }
        } else {
            #pragma unroll
            for (int e = 0; e < 4; ++e) {
                int bC = kc * 4 + e;
                d2u[sgl * 576 + bC * 36 + r]      = 0;
                d2u[sgl * 576 + bC * 36 + 16 + r] = 0;
            }
        }
    }

    // ---- phase3: own 10 slabs -> hdec n in [4*m0+16q, +16) ----
    {
        f32x4 acc = (f32x4){0.f, 0.f, 0.f, 0.f};
        #pragma unroll
        for (int kap = 0; kap < 10; ++kap) {
            short8 A = *(const short8*)(d2u + kap * 576 + r * 36 + kc * 8);
            short8 B = *(const short8*)(g_dec2B + r * 320 + kap * 32 + kc * 8);
            acc = __builtin_amdgcn_mfma_f32_16x16x32_bf16(A, B, acc, 0, 0, 0);
        }
        const int n = 4 * m0 + 16 * q + r;
        #pragma unroll
        for (int e = 0; e < 4; ++e) {
            int b = kc * 4 + e;
            hdec[((size_t)bblk * 16 + b) * 512 + n] = f2bf_bits(fmaxf(acc[e] + bia2, 0.f));
        }
    }
}

// =====================================================================
// Kernel B: out = hdec @ g_muwb^T + mu_b. RETILED: 64x128 output tiles
// -> 512 blocks = 2/CU (was 256 = 1/CU, zero inter-block overlap for a
// 16-barrier kernel). Per-element K-accumulation chains unchanged ->
// bitwise identical C.
// =====================================================================
__global__ __launch_bounds__(256)
void k_mu_gemm(const unsigned short* __restrict__ A,
               const float* __restrict__ bias,
               float* __restrict__ C)
{
    __shared__ unsigned short As[64 * 32];
    __shared__ unsigned short Bs[128 * 32];
    const int tid  = threadIdx.x;
    const int lane = tid & 63;
    const int wid  = tid >> 6;
    const int bm   = blockIdx.x & 127;      // 128 m-tiles of 64 rows
    const int bn   = blockIdx.x >> 7;       // 4 n-tiles of 128 cols
    const int wm   = (wid & 1) * 32;
    const int wn   = (wid >> 1) * 64;
    const unsigned short* Ab = A + (size_t)bm * 64 * 512;
    const unsigned short* Bb = g_muwb + (size_t)bn * 128 * 512;

    f32x4 acc[2][4];
    #pragma unroll
    for (int i = 0; i < 2; ++i)
        #pragma unroll
        for (int j = 0; j < 4; ++j)
            acc[i][j] = (f32x4){0.f, 0.f, 0.f, 0.f};

    const int r  = lane & 15;
    const int kc = lane >> 4;

    for (int ks = 0; ks < 16; ++ks) {
        const int k0 = ks * 32;
        {   // A: 64x32 = 4 KB, single shot
            const int off  = tid * 16;
            const int row  = off >> 6;
            const int colb = off & 63;
            const char* ga = (const char*)Ab + (size_t)row * 1024 + (size_t)k0 * 2 + colb;
            char* la = (char*)As + wid * 1024;
            __builtin_amdgcn_global_load_lds((AS1 const unsigned int*)ga, (AS3 unsigned int*)la, 16, 0, 0);
        }
        #pragma unroll
        for (int q = 0; q < 2; ++q) {   // B: 128x32 = 8 KB
            const int off  = q * 4096 + tid * 16;
            const int row  = off >> 6;
            const int colb = off & 63;
            const char* gb = (const char*)Bb + (size_t)row * 1024 + (size_t)k0 * 2 + colb;
            char* lb = (char*)Bs + q * 4096 + wid * 1024;
            __builtin_amdgcn_global_load_lds((AS1 const unsigned int*)gb, (AS3 unsigned int*)lb, 16, 0, 0);
        }
        __syncthreads();

        short8 af[2], bf[4];
        #pragma unroll
        for (int mf = 0; mf < 2; ++mf)
            af[mf] = *(const short8*)&As[(wm + mf * 16 + r) * 32 + kc * 8];
        #pragma unroll
        for (int nf = 0; nf < 4; ++nf)
            bf[nf] = *(const short8*)&Bs[(wn + nf * 16 + r) * 32 + kc * 8];
        #pragma unroll
        for (int mf = 0; mf < 2; ++mf)
            #pragma unroll
            for (int nf = 0; nf < 4; ++nf)
                acc[mf][nf] = __builtin_amdgcn_mfma_f32_16x16x32_bf16(af[mf], bf[nf], acc[mf][nf], 0, 0, 0);
        __syncthreads();
    }

    const int col = lane & 15;
    const int rg  = lane >> 4;
    float bv[4];
    #pragma unroll
    for (int nf = 0; nf < 4; ++nf)
        bv[nf] = bias[bn * 128 + wn + nf * 16 + col];
    #pragma unroll
    for (int mf = 0; mf < 2; ++mf)
        #pragma unroll
        for (int nf = 0; nf < 4; ++nf)
            #pragma unroll
            for (int e = 0; e < 4; ++e) {
                int m = bm * 64 + wm + mf * 16 + rg * 4 + e;
                int n = bn * 128 + wn + nf * 16 + col;
                C[(size_t)m * 512 + n] = acc[mf][nf][e] + bv[nf];
            }
}

// =====================================================================
extern "C" void kernel_launch(void* const* d_in, const int* in_sizes, int n_in,
                              void* d_out, int out_size, void* d_ws, size_t ws_size,
                              hipStream_t stream) {
    const float* x    = (const float*)d_in[0];
    const float* ew0  = (const float*)d_in[1];
    const float* eb0  = (const float*)d_in[2];
    const float* ew1  = (const float*)d_in[3];
    const float* eb1  = (const float*)d_in[4];
    const float* ew2  = (const float*)d_in[5];
    const float* eb2  = (const float*)d_in[6];
    const float* cb   = (const float*)d_in[7];
    const float* embw = (const float*)d_in[8];
    const float* embb = (const float*)d_in[9];
    const float* dw0  = (const float*)d_in[10];
    const float* db0  = (const float*)d_in[11];
    const float* dw1  = (const float*)d_in[12];
    const float* db1  = (const float*)d_in[13];
    const float* dw2  = (const float*)d_in[14];
    const float* db2  = (const float*)d_in[15];
    const float* muw  = (const float*)d_in[16];
    const float* mub  = (const float*)d_in[17];
    const int*   spk  = (const int*)d_in[18];

    float* zout = (float*)d_out;
    float* cout = zout + (size_t)8192 * 64;
    float* yout = zout + (size_t)2 * 8192 * 64;
    float* din_g = zout + (size_t)8192 * 576;             // tail of yout

    unsigned short* hdec = (unsigned short*)d_ws;

    k_prep<<<dim3(1247), dim3(256), 0, stream>>>(muw, dw1, dw2, ew1, cb, embw);

    k_encoder<<<dim3(4096), dim3(256), 0, stream>>>(
        x, ew0, eb0, eb1, ew2, eb2, zout);

    k_enc_tail<<<dim3(1024), dim3(256), 0, stream>>>(
        zout, cb, embb, spk, cout, din_g);

    k_decoder<<<dim3(4096), dim3(256), 0, stream>>>(din_g, dw0, db0, db1, db2, hdec);

    k_mu_gemm<<<dim3(512), dim3(256), 0, stream>>>(hdec, mub, yout);
}

// Round 16
// 157.119 us; speedup vs baseline: 1.0448x; 1.0448x over previous
//
#include <hip/hip_runtime.h>
#include <hip/hip_bf16.h>

// ---------- helpers ----------
__device__ __forceinline__ float bits2f(unsigned int b) {
    union { unsigned int u; float f; } v; v.u = b; return v.f;
}
__device__ __forceinline__ unsigned short f2bf_bits(float f) {
    union { float f; unsigned int u; } v; v.f = f;
    return (unsigned short)((v.u + 0x7fffu + ((v.u >> 16) & 1u)) >> 16);
}
__device__ __forceinline__ unsigned short f2h_bits(_Float16 h) {
    union { _Float16 f; unsigned short u; } v; v.f = h; return v.u;
}

typedef __attribute__((ext_vector_type(8))) short short8;
typedef __attribute__((ext_vector_type(4))) float f32x4;
typedef _Float16 f16x8 __attribute__((ext_vector_type(8)));

#define AS1 __attribute__((address_space(1)))
#define AS3 __attribute__((address_space(3)))

// prep-built tables (rewritten every launch: deterministic)
__device__ __align__(16) unsigned short g_muwb[512 * 512];
__device__ __align__(16) unsigned short g_dec1B[4096];   // [p][tap][o][i] bf16
__device__ __align__(16) unsigned short g_dec2B[5120];   // [j(16)][k(320)] bf16
__device__ __align__(16) unsigned short g_encBh[4096];   // [j][o][i] f16 hi
__device__ __align__(16) unsigned short g_encBl[4096];   // [j][o][i] f16 lo*2048
__device__ float g_cc[512];                              // codebook row norms
__device__ __align__(16) float g_cbT[64 * 512];          // codebook^T [d][c]
__device__ __align__(16) float g_embwT[164 * 64];        // embw^T [k][j]

// =====================================================================
// Prep: mu_w->bf16; decoder B-tables; enc-L1 f16-split B; cc norms;
// codebook^T and embw^T for coalesced tail access
// =====================================================================
__global__ __launch_bounds__(256)
void k_prep(const float* __restrict__ muw, const float* __restrict__ dw1,
            const float* __restrict__ dw2, const float* __restrict__ ew1,
            const float* __restrict__ cb, const float* __restrict__ embw)
{
    int idx = blockIdx.x * 256 + threadIdx.x;
    if (idx < 262144) { g_muwb[idx] = f2bf_bits(muw[idx]); return; }
    int e = idx - 262144;
    if (e < 4096) {
        const int jsel[4] = {1, 3, 2, 0};
        int pt = e >> 10, o = (e >> 5) & 31, i = e & 31;
        g_dec1B[e] = f2bf_bits(dw1[i * 128 + o * 4 + jsel[pt]]);
        return;
    }
    int f = e - 4096;
    if (f < 5120) {
        int j = f / 320, k = f - j * 320;
        int lam = k >> 5, i = k & 31, q = j >> 1;
        float v = 0.f;
        if ((j & 1) == 0) {
            if (lam == q + 1) v = dw2[4 * i + 1];
            else if (lam == q) v = dw2[4 * i + 3];
        } else {
            if (lam == q + 1) v = dw2[4 * i + 2];
            else if (lam == q + 2) v = dw2[4 * i + 0];
        }
        g_dec2B[f] = f2bf_bits(v);
        return;
    }
    int g = f - 5120;
    if (g < 4096) {
        // g = j*1024 + o*32 + i ; w1 flat [o][i][j]
        int j = g >> 10, o = (g >> 5) & 31, i = g & 31;
        float w = ew1[o * 128 + i * 4 + j];
        _Float16 wh = (_Float16)w;
        _Float16 wl = (_Float16)((w - (float)wh) * 2048.0f);
        g_encBh[g] = f2h_bits(wh);
        g_encBl[g] = f2h_bits(wl);
        return;
    }
    int h = g - 4096;
    if (h < 512) {
        const float4* cp = (const float4*)(cb + (size_t)h * 64);
        float cc2 = 0.f;
        #pragma unroll
        for (int q = 0; q < 16; ++q) {
            float4 u = cp[q];
            cc2 += u.x * u.x + u.y * u.y + u.z * u.z + u.w * u.w;
        }
        g_cc[h] = cc2;
        return;
    }
    int m = h - 512;
    if (m < 32768) {                       // cbT[d][c] = cb[c][d]
        int d = m >> 9, c = m & 511;
        g_cbT[m] = cb[(size_t)c * 64 + d];
        return;
    }
    int n2 = m - 32768;
    if (n2 < 10496) {                      // embwT[k][j] = embw[j][k]
        int k = n2 >> 6, j = n2 & 63;
        g_embwT[n2] = embw[(size_t)j * 164 + k];
    }
}

// =====================================================================
// Kernel E-front: encoder x -> z. TWO WAVES PER ROW, m-halved.
// (round-13 structure RESTORED verbatim — round-14's shuffle-reuse
// serialized the tile chain through cross-lane ops and regressed;
// redundant independent FMAs are cheaper than dependent shuffles.)
// =====================================================================
__global__ __launch_bounds__(256, 2)
void k_encoder(const float* __restrict__ x,
               const float* __restrict__ ew0, const float* __restrict__ eb0,
               const float* __restrict__ eb1,
               const float* __restrict__ ew2, const float* __restrict__ eb2,
               float* __restrict__ z_out)
{
    const int tid  = threadIdx.x;
    const int lane = tid & 63;
    const int w    = tid >> 6;                 // wave 0..3
    const int rloc = w >> 1;                   // row-in-block 0..1
    const int wh   = w & 1;                    // m-half 0/1
    const int row  = blockIdx.x * 2 + rloc;    // 0..8191

    __shared__ __align__(16) float POOL[2 * 4688];
    float* ws = POOL + rloc * 4688;
    float* xs = ws;                            // data at +3
    float* h2 = ws + 520;                      // rows ch*130, data +4

    const int r = lane & 15, kc = lane >> 4;
    const float biaN0 = eb1[r], biaN1 = eb1[16 + r];

    // ---- stage x: each wave stages its half of the row (coalesced) ----
    const float* xrow = x + (size_t)row * 512;
    #pragma unroll
    for (int q = 0; q < 4; ++q) {
        const int ch = wh * 4 + q;
        xs[3 + lane + 64 * ch] = xrow[lane + 64 * ch];
    }
    if (wh == 0) {
        if (lane < 3) xs[lane] = 0.f;
        // h2 guards gi = 0..63 (rows 0..31 at +2/+3)
        h2[(lane >> 1) * 130 + 2 + (lane & 1)] = 0.f;
    } else {
        if (lane < 3) xs[515 + lane] = 0.f;
        if (lane < 2) { int gi = 64 + lane; h2[(gi >> 1) * 130 + 2 + (gi & 1)] = 0.f; }
    }

    // ---- B-fragments: m-independent, load once per wave ----
    f16x8 Bh[2][4], Bl[2][4];
    #pragma unroll
    for (int nt = 0; nt < 2; ++nt)
        #pragma unroll
        for (int j = 0; j < 4; ++j) {
            const int off = (j * 32 + nt * 16 + r) * 32 + kc * 8;
            Bh[nt][j] = *(const f16x8*)(g_encBh + off);
            Bl[nt][j] = *(const f16x8*)(g_encBl + off);
        }
    // ---- L0 weights: hoisted once per lane ----
    float4 Wv[8]; float b0v[8];
    #pragma unroll
    for (int i = 0; i < 8; ++i) {
        Wv[i]  = *(const float4*)(ew0 + (kc * 8 + i) * 4);
        b0v[i] = eb0[kc * 8 + i];
    }
    __syncthreads();

    // ---- 4 M-tiles (this wave's half): fused L0 (registers) + MFMA -> h2 ----
    #pragma unroll 2
    for (int mi = 0; mi < 4; ++mi) {
        const int m = 4 * wh + mi;
        const int t2 = m * 16 + r;
        float xw[10];
        {
            const float* xwin = xs + 4 * t2;   // = xs[3 + (4*t2-3) + q]
            #pragma unroll
            for (int q = 0; q < 10; ++q) xw[q] = xwin[q];
        }
        f16x8 ah0, ah1, ah2, ah3, al0, al1, al2, al3;
        #pragma unroll
        for (int i = 0; i < 8; ++i) {
            const float4 W = Wv[i];
            const float b0 = b0v[i];
            // identical expression shape to the old L0 (same FMA contraction)
            float v0 = fmaxf(b0 + xw[0] * W.x + xw[1] * W.y + xw[2] * W.z + xw[3] * W.w, 0.f);
            float v1 = fmaxf(b0 + xw[2] * W.x + xw[3] * W.y + xw[4] * W.z + xw[5] * W.w, 0.f);
            float v2 = fmaxf(b0 + xw[4] * W.x + xw[5] * W.y + xw[6] * W.z + xw[7] * W.w, 0.f);
            float v3 = fmaxf(b0 + xw[6] * W.x + xw[7] * W.y + xw[8] * W.z + xw[9] * W.w, 0.f);
            _Float16 hh0 = (_Float16)v0, hh1 = (_Float16)v1;
            _Float16 hh2 = (_Float16)v2, hh3 = (_Float16)v3;
            _Float16 ll0 = (_Float16)((v0 - (float)hh0) * 2048.0f);
            _Float16 ll1 = (_Float16)((v1 - (float)hh1) * 2048.0f);
            _Float16 ll2 = (_Float16)((v2 - (float)hh2) * 2048.0f);
            _Float16 ll3 = (_Float16)((v3 - (float)hh3) * 2048.0f);
            ah0[i] = hh0; al0[i] = ll0;
            ah1[i] = hh1; al1[i] = ll1;
            ah2[i] = hh2; al2[i] = ll2;
            ah3[i] = hh3; al3[i] = ll3;
        }
        {
            const f16x8 Z8 = {(_Float16)0.f, (_Float16)0.f, (_Float16)0.f, (_Float16)0.f,
                              (_Float16)0.f, (_Float16)0.f, (_Float16)0.f, (_Float16)0.f};
            if (t2 == 0)   { ah0 = Z8; al0 = Z8; }    // t = -1 guard
            if (t2 == 127) { ah3 = Z8; al3 = Z8; }    // t = 256 guard
        }
        const int t0 = m * 16;
        #pragma unroll
        for (int nt = 0; nt < 2; ++nt) {
            f32x4 ahh = (f32x4){0.f, 0.f, 0.f, 0.f};
            f32x4 am  = (f32x4){0.f, 0.f, 0.f, 0.f};
            f32x4 all_= (f32x4){0.f, 0.f, 0.f, 0.f};
            ahh = __builtin_amdgcn_mfma_f32_16x16x32_f16(ah0, Bh[nt][0], ahh, 0, 0, 0);
            am  = __builtin_amdgcn_mfma_f32_16x16x32_f16(ah0, Bl[nt][0], am,  0, 0, 0);
            am  = __builtin_amdgcn_mfma_f32_16x16x32_f16(al0, Bh[nt][0], am,  0, 0, 0);
            all_= __builtin_amdgcn_mfma_f32_16x16x32_f16(al0, Bl[nt][0], all_,0, 0, 0);
            ahh = __builtin_amdgcn_mfma_f32_16x16x32_f16(ah1, Bh[nt][1], ahh, 0, 0, 0);
            am  = __builtin_amdgcn_mfma_f32_16x16x32_f16(ah1, Bl[nt][1], am,  0, 0, 0);
            am  = __builtin_amdgcn_mfma_f32_16x16x32_f16(al1, Bh[nt][1], am,  0, 0, 0);
            all_= __builtin_amdgcn_mfma_f32_16x16x32_f16(al1, Bl[nt][1], all_,0, 0, 0);
            ahh = __builtin_amdgcn_mfma_f32_16x16x32_f16(ah2, Bh[nt][2], ahh, 0, 0, 0);
            am  = __builtin_amdgcn_mfma_f32_16x16x32_f16(ah2, Bl[nt][2], am,  0, 0, 0);
            am  = __builtin_amdgcn_mfma_f32_16x16x32_f16(al2, Bh[nt][2], am,  0, 0, 0);
            all_= __builtin_amdgcn_mfma_f32_16x16x32_f16(al2, Bl[nt][2], all_,0, 0, 0);
            ahh = __builtin_amdgcn_mfma_f32_16x16x32_f16(ah3, Bh[nt][3], ahh, 0, 0, 0);
            am  = __builtin_amdgcn_mfma_f32_16x16x32_f16(ah3, Bl[nt][3], am,  0, 0, 0);
            am  = __builtin_amdgcn_mfma_f32_16x16x32_f16(al3, Bh[nt][3], am,  0, 0, 0);
            all_= __builtin_amdgcn_mfma_f32_16x16x32_f16(al3, Bl[nt][3], all_,0, 0, 0);
            const float bia = nt ? biaN1 : biaN0;
            float* orow = h2 + (nt * 16 + r) * 130 + 4 + t0 + kc * 4;
            #pragma unroll
            for (int e = 0; e < 4; ++e)
                orow[e] = fmaxf(ahh[e] + 4.8828125e-4f * am[e]
                                + 2.384185791015625e-07f * all_[e] + bia, 0.f);
        }
    }
    __syncthreads();

    // ---- L2: UNCHANGED, on wh=0 wave only; lane = t' -> bitwise z ----
    if (wh == 0) {
        const int t = lane;
        float pg[4];
        #pragma unroll
        for (int gg = 0; gg < 4; ++gg) {
            float p = 0.f;
            #pragma unroll
            for (int ii = 0; ii < 8; ++ii) {
                const int i = gg * 8 + ii;
                const float4 W = *(const float4*)(ew2 + i * 4);
                const float* hr = h2 + i * 130 + 4;
                p += hr[2 * t - 1] * W.x + hr[2 * t] * W.y
                   + hr[2 * t + 1] * W.z + hr[2 * t + 2] * W.w;
            }
            pg[gg] = p;
        }
        float zv = fmaxf(pg[0] + pg[1] + pg[2] + pg[3] + eb2[0], 0.f);
        z_out[(size_t)row * 64 + t] = zv;
    }
}

// =====================================================================
// Kernel E-tail: batched VQ + code + emb. 1024 blocks x 8 rows, 256 thr.
// (round-2 structure, unchanged)
// =====================================================================
__global__ __launch_bounds__(256)
void k_enc_tail(const float* __restrict__ z_in, const float* __restrict__ cb,
                const float* __restrict__ embb,
                const int* __restrict__ spk,
                float* __restrict__ code_out, float* __restrict__ din_g)
{
    const int blk  = blockIdx.x;          // 0..1023
    const int tid  = threadIdx.x;
    const int lane = tid & 63;
    const int wv   = tid >> 6;            // wave 0..3

    __shared__ __align__(16) float zs[8][64];
    __shared__ __align__(16) float csf[8][64];
    __shared__ float zzv[8];
    __shared__ float redv[4][8];
    __shared__ int   redi[4][8];
    __shared__ int   sidxs[8];

    const int jq = tid & 63;              // j / column index
    const int rq = tid >> 6;              // row group 0..3

    // ---- Phase A: load 8 z rows, coalesced ----
    #pragma unroll
    for (int ch = 0; ch < 2; ++ch) {
        const int rr = rq + ch * 4;
        zs[rr][jq] = z_in[((size_t)blk * 8 + rr) * 64 + jq];
    }
    __syncthreads();

    // ---- Phase B: zz butterfly emulation (threads 0..7, one row each) ----
    if (tid < 8) {
        float4 zr[16];
        #pragma unroll
        for (int q = 0; q < 16; ++q) zr[q] = *(const float4*)(&zs[tid][4 * q]);
        float u[32];
        #pragma unroll
        for (int q = 0; q < 8; ++q) {
            u[4 * q + 0] = __fadd_rn(__fmul_rn(zr[q].x, zr[q].x), __fmul_rn(zr[q + 8].x, zr[q + 8].x));
            u[4 * q + 1] = __fadd_rn(__fmul_rn(zr[q].y, zr[q].y), __fmul_rn(zr[q + 8].y, zr[q + 8].y));
            u[4 * q + 2] = __fadd_rn(__fmul_rn(zr[q].z, zr[q].z), __fmul_rn(zr[q + 8].z, zr[q + 8].z));
            u[4 * q + 3] = __fadd_rn(__fmul_rn(zr[q].w, zr[q].w), __fmul_rn(zr[q + 8].w, zr[q + 8].w));
        }
        #pragma unroll
        for (int off = 16; off; off >>= 1)
            #pragma unroll
            for (int i = 0; i < off; ++i) u[i] = __fadd_rn(u[i], u[i + off]);
        zzv[tid] = u[0];
    }

    // ---- Phase C: dot accumulation, codes c0=tid, c1=tid+256 ----
    float acc[8][2];
    #pragma unroll
    for (int r2 = 0; r2 < 8; ++r2) { acc[r2][0] = 0.f; acc[r2][1] = 0.f; }

    #pragma unroll 4
    for (int dq = 0; dq < 16; ++dq) {
        float4 zv[8];
        #pragma unroll
        for (int r2 = 0; r2 < 8; ++r2) zv[r2] = *(const float4*)(&zs[r2][4 * dq]);
        #pragma unroll
        for (int dd = 0; dd < 4; ++dd) {
            const int d = 4 * dq + dd;
            const float w0 = g_cbT[d * 512 + tid];
            const float w1 = g_cbT[d * 512 + 256 + tid];
            #pragma unroll
            for (int r2 = 0; r2 < 8; ++r2) {
                const float zd = (dd == 0) ? zv[r2].x : (dd == 1) ? zv[r2].y
                               : (dd == 2) ? zv[r2].z : zv[r2].w;
                acc[r2][0] = fmaf(w0, zd, acc[r2][0]);
                acc[r2][1] = fmaf(w1, zd, acc[r2][1]);
            }
        }
    }
    __syncthreads();     // zzv ready

    // ---- Phase D: dist + lexicographic argmin per row ----
    {
        const float cc0 = g_cc[tid], cc1 = g_cc[tid + 256];
        float best[8]; int bidx[8];
        #pragma unroll
        for (int r2 = 0; r2 < 8; ++r2) {
            const float zz = zzv[r2];
            float d0 = 0.5f * (zz - 2.f * acc[r2][0] + cc0);
            float d1 = 0.5f * (zz - 2.f * acc[r2][1] + cc1);
            best[r2] = d0; bidx[r2] = tid;
            if (d1 < best[r2]) { best[r2] = d1; bidx[r2] = tid + 256; }
        }
        #pragma unroll
        for (int off = 32; off; off >>= 1) {
            #pragma unroll
            for (int r2 = 0; r2 < 8; ++r2) {
                float od = __shfl_down(best[r2], off);
                int   oi = __shfl_down(bidx[r2], off);
                if (od < best[r2] || (od == best[r2] && oi < bidx[r2])) {
                    best[r2] = od; bidx[r2] = oi;
                }
            }
        }
        if (lane == 0) {
            #pragma unroll
            for (int r2 = 0; r2 < 8; ++r2) { redv[wv][r2] = best[r2]; redi[wv][r2] = bidx[r2]; }
        }
    }
    __syncthreads();
    if (tid < 8) {
        float bd = redv[0][tid]; int bi = redi[0][tid];
        #pragma unroll
        for (int w = 1; w < 4; ++w)
            if (redv[w][tid] < bd || (redv[w][tid] == bd && redi[w][tid] < bi)) {
                bd = redv[w][tid]; bi = redi[w][tid];
            }
        sidxs[tid] = min(max(bi, 0), 511);
    }
    __syncthreads();

    // ---- Phase E: code copy + embedding (coalesced via embwT) ----
    #pragma unroll
    for (int ch = 0; ch < 2; ++ch) {
        const int rr = rq + ch * 4;
        const int sx = sidxs[rr];
        const float cv = cb[(size_t)sx * 64 + jq];
        code_out[((size_t)blk * 8 + rr) * 64 + jq] = cv;   // bit-exact codebook row
        csf[rr][jq] = cv;
    }
    __syncthreads();
    #pragma unroll
    for (int ch = 0; ch < 2; ++ch) {
        const int rr = rq + ch * 4;
        const size_t b2 = (size_t)blk * 8 + rr;
        float pg[4];
        #pragma unroll
        for (int gg = 0; gg < 4; ++gg) {
            float p = 0.f;
            #pragma unroll
            for (int q = 0; q < 4; ++q) {
                const int k0 = 16 * gg + 4 * q;
                const float w0 = g_embwT[(k0 + 0) * 64 + jq];
                const float w1 = g_embwT[(k0 + 1) * 64 + jq];
                const float w2 = g_embwT[(k0 + 2) * 64 + jq];
                const float w3 = g_embwT[(k0 + 3) * 64 + jq];
                p += w0 * csf[rr][k0 + 0] + w1 * csf[rr][k0 + 1]
                   + w2 * csf[rr][k0 + 2] + w3 * csf[rr][k0 + 3];
            }
            pg[gg] = p;
        }
        float a = pg[0] + pg[1] + pg[2] + pg[3]
                + embb[jq] + g_embwT[(64 + spk[b2]) * 64 + jq];
        din_g[b2 * 64 + jq] = a;
    }
}

// =====================================================================
// Kernel D: decoder, WAVE-INDEPENDENT n-QUARTERS, ONE barrier.
// (round-13 structure, unchanged)
// =====================================================================
__global__ __launch_bounds__(256)
void k_decoder(const float* __restrict__ din_g,
               const float* __restrict__ dw0, const float* __restrict__ db0,
               const float* __restrict__ db1, const float* __restrict__ db2,
               unsigned short* __restrict__ hdec)
{
    const int gidx = blockIdx.x;            // 0..4095
    const int bblk = gidx >> 3;             // row group 0..511
    const int m0   = (gidx & 7) * 16;       // m0 step
    const int tid  = threadIdx.x;
    const int lane = tid & 63;
    const int q    = tid >> 6;              // wave = n-quarter 0..3

    __shared__ __align__(16) float        dins[16 * 68];
    __shared__ __align__(16) unsigned int d2c[4][10 * 16 * 18];   // per-wave

    // ---- cooperative dins load (unchanged expressions) ----
    {
        int b = tid >> 4, j4 = tid & 15;
        float4 v = *(const float4*)(din_g + ((size_t)bblk * 16 + b) * 64 + j4 * 4);
        float* dr = dins + b * 68 + 1 + j4 * 4;
        dr[0] = v.x; dr[1] = v.y; dr[2] = v.z; dr[3] = v.w;
        if (j4 == 0) { dins[b * 68] = 0.f; dins[b * 68 + 65] = 0.f; }
    }

    const int r = lane & 15, kc = lane >> 4;
    const float bia2 = db2[0];

    // ---- conv weights for this lane's 4 pairs pp = 4kc+j ----
    float4 Wa[4], Wb[4]; float ba0v[4], ba1v[4];
    #pragma unroll
    for (int j = 0; j < 4; ++j) {
        const int pp = 4 * kc + j;
        Wa[j] = *(const float4*)(dw0 + 8 * pp);
        Wb[j] = *(const float4*)(dw0 + 8 * pp + 4);
        ba0v[j] = db0[2 * pp];
        ba1v[j] = db0[2 * pp + 1];
    }
    // ---- phase2 B-fragments, both parities (static indexing) ----
    short8 B00[2], B10[2], B01[2], B11[2];
    #pragma unroll
    for (int p = 0; p < 2; ++p) {
        const unsigned short* Bp = g_dec1B + p * 2048;
        B00[p] = *(const short8*)(Bp + (r) * 32 + kc * 8);
        B10[p] = *(const short8*)(Bp + 1024 + (r) * 32 + kc * 8);
        B01[p] = *(const short8*)(Bp + (16 + r) * 32 + kc * 8);
        B11[p] = *(const short8*)(Bp + 1024 + (16 + r) * 32 + kc * 8);
    }
    const float bv0 = db1[r], bv1 = db1[16 + r];
    __syncthreads();                        // the ONLY barrier

    // ---- phase1: conv -> d1 in registers: d1r[tl][j], tau_global = 4q+tl ----
    unsigned int d1r[6][4];
    const float* dn = dins + r * 68 + 1;
    #pragma unroll
    for (int tl = 0; tl < 6; ++tl) {
        const int s = m0 - 1 + 4 * q + tl;
        const bool inb = (s >= 0 && s < 128);
        const int m = s >> 1;
        #pragma unroll
        for (int j = 0; j < 4; ++j) {
            unsigned int pk = 0u;
            if (inb) {
                float v0, v1;
                if (s & 1) { v0 = ba0v[j] + dn[m] * Wa[j].z + dn[m + 1] * Wa[j].x;
                             v1 = ba1v[j] + dn[m] * Wb[j].z + dn[m + 1] * Wb[j].x; }
                else       { v0 = ba0v[j] + dn[m] * Wa[j].y + dn[m - 1] * Wa[j].w;
                             v1 = ba1v[j] + dn[m] * Wb[j].y + dn[m - 1] * Wb[j].w; }
                pk = (unsigned int)f2bf_bits(fmaxf(v0, 0.f))
                   | ((unsigned int)f2bf_bits(fmaxf(v1, 0.f)) << 16);
            }
            d1r[tl][j] = pk;
        }
    }

    // ---- phase2: 10 slabs, fully unrolled; writes to PRIVATE d2c ----
    unsigned short* d2u = (unsigned short*)(d2c[q]);
    const int tb = 2 * m0 - 1 + 8 * q;
    #pragma unroll
    for (int sgl = 0; sgl < 10; ++sgl) {
        const int p     = 1 - (sgl & 1);            // compile-time
        const int tauAl = (sgl + 1) >> 1;           // compile-time
        const int tauBl = p ? tauAl + 1 : tauAl - 1;
        const int t = tb + sgl;
        if (t >= 0 && t < 256) {
            union { unsigned int u[4]; short8 s8; } am_, ap_;
            am_.u[0] = d1r[tauAl][0]; am_.u[1] = d1r[tauAl][1];
            am_.u[2] = d1r[tauAl][2]; am_.u[3] = d1r[tauAl][3];
            ap_.u[0] = d1r[tauBl][0]; ap_.u[1] = d1r[tauBl][1];
            ap_.u[2] = d1r[tauBl][2]; ap_.u[3] = d1r[tauBl][3];
            f32x4 acc0 = (f32x4){0.f, 0.f, 0.f, 0.f};
            f32x4 acc1 = (f32x4){0.f, 0.f, 0.f, 0.f};
            acc0 = __builtin_amdgcn_mfma_f32_16x16x32_bf16(am_.s8, B00[p], acc0, 0, 0, 0);
            acc0 = __builtin_amdgcn_mfma_f32_16x16x32_bf16(ap_.s8, B10[p], acc0, 0, 0, 0);
            acc1 = __builtin_amdgcn_mfma_f32_16x16x32_bf16(am_.s8, B01[p], acc1, 0, 0, 0);
            acc1 = __builtin_amdgcn_mfma_f32_16x16x32_bf16(ap_.s8, B11[p], acc1, 0, 0, 0);
            #pragma unroll
            for (int e = 0; e < 4; ++e) {
                int bC = kc * 4 + e;
                d2u[sgl * 576 + bC * 36 + r]      = f2bf_bits(fmaxf(acc0[e] + bv0, 0.f));
                d2u[sgl * 576 + bC * 36 + 16 + r] = f2bf_bits(fmaxf(acc1[e] + bv1, 0.f));
            }
        } else {
            #pragma unroll
            for (int e = 0; e < 4; ++e) {
                int bC = kc * 4 + e;
                d2u[sgl * 576 + bC * 36 + r]      = 0;
                d2u[sgl * 576 + bC * 36 + 16 + r] = 0;
            }
        }
    }

    // ---- phase3: own 10 slabs -> hdec n in [4*m0+16q, +16) ----
    {
        f32x4 acc = (f32x4){0.f, 0.f, 0.f, 0.f};
        #pragma unroll
        for (int kap = 0; kap < 10; ++kap) {
            short8 A = *(const short8*)(d2u + kap * 576 + r * 36 + kc * 8);
            short8 B = *(const short8*)(g_dec2B + r * 320 + kap * 32 + kc * 8);
            acc = __builtin_amdgcn_mfma_f32_16x16x32_bf16(A, B, acc, 0, 0, 0);
        }
        const int n = 4 * m0 + 16 * q + r;
        #pragma unroll
        for (int e = 0; e < 4; ++e) {
            int b = kc * 4 + e;
            hdec[((size_t)bblk * 16 + b) * 512 + n] = f2bf_bits(fmaxf(acc[e] + bia2, 0.f));
        }
    }
}

// =====================================================================
// Kernel B: out = hdec @ g_muwb^T + mu_b. RETILED: 64x128 output tiles
// -> 512 blocks = 2/CU (kept from round 14: bitwise-identical math,
// doubles inter-block overlap for a 16-barrier kernel).
// =====================================================================
__global__ __launch_bounds__(256)
void k_mu_gemm(const unsigned short* __restrict__ A,
               const float* __restrict__ bias,
               float* __restrict__ C)
{
    __shared__ unsigned short As[64 * 32];
    __shared__ unsigned short Bs[128 * 32];
    const int tid  = threadIdx.x;
    const int lane = tid & 63;
    const int wid  = tid >> 6;
    const int bm   = blockIdx.x & 127;      // 128 m-tiles of 64 rows
    const int bn   = blockIdx.x >> 7;       // 4 n-tiles of 128 cols
    const int wm   = (wid & 1) * 32;
    const int wn   = (wid >> 1) * 64;
    const unsigned short* Ab = A + (size_t)bm * 64 * 512;
    const unsigned short* Bb = g_muwb + (size_t)bn * 128 * 512;

    f32x4 acc[2][4];
    #pragma unroll
    for (int i = 0; i < 2; ++i)
        #pragma unroll
        for (int j = 0; j < 4; ++j)
            acc[i][j] = (f32x4){0.f, 0.f, 0.f, 0.f};

    const int r  = lane & 15;
    const int kc = lane >> 4;

    for (int ks = 0; ks < 16; ++ks) {
        const int k0 = ks * 32;
        {   // A: 64x32 = 4 KB, single shot
            const int off  = tid * 16;
            const int row  = off >> 6;
            const int colb = off & 63;
            const char* ga = (const char*)Ab + (size_t)row * 1024 + (size_t)k0 * 2 + colb;
            char* la = (char*)As + wid * 1024;
            __builtin_amdgcn_global_load_lds((AS1 const unsigned int*)ga, (AS3 unsigned int*)la, 16, 0, 0);
        }
        #pragma unroll
        for (int q = 0; q < 2; ++q) {   // B: 128x32 = 8 KB
            const int off  = q * 4096 + tid * 16;
            const int row  = off >> 6;
            const int colb = off & 63;
            const char* gb = (const char*)Bb + (size_t)row * 1024 + (size_t)k0 * 2 + colb;
            char* lb = (char*)Bs + q * 4096 + wid * 1024;
            __builtin_amdgcn_global_load_lds((AS1 const unsigned int*)gb, (AS3 unsigned int*)lb, 16, 0, 0);
        }
        __syncthreads();

        short8 af[2], bf[4];
        #pragma unroll
        for (int mf = 0; mf < 2; ++mf)
            af[mf] = *(const short8*)&As[(wm + mf * 16 + r) * 32 + kc * 8];
        #pragma unroll
        for (int nf = 0; nf < 4; ++nf)
            bf[nf] = *(const short8*)&Bs[(wn + nf * 16 + r) * 32 + kc * 8];
        #pragma unroll
        for (int mf = 0; mf < 2; ++mf)
            #pragma unroll
            for (int nf = 0; nf < 4; ++nf)
                acc[mf][nf] = __builtin_amdgcn_mfma_f32_16x16x32_bf16(af[mf], bf[nf], acc[mf][nf], 0, 0, 0);
        __syncthreads();
    }

    const int col = lane & 15;
    const int rg  = lane >> 4;
    float bv[4];
    #pragma unroll
    for (int nf = 0; nf < 4; ++nf)
        bv[nf] = bias[bn * 128 + wn + nf * 16 + col];
    #pragma unroll
    for (int mf = 0; mf < 2; ++mf)
        #pragma unroll
        for (int nf = 0; nf < 4; ++nf)
            #pragma unroll
            for (int e = 0; e < 4; ++e) {
                int m = bm * 64 + wm + mf * 16 + rg * 4 + e;
                int n = bn * 128 + wn + nf * 16 + col;
                C[(size_t)m * 512 + n] = acc[mf][nf][e] + bv[nf];
            }
}

// =====================================================================
extern "C" void kernel_launch(void* const* d_in, const int* in_sizes, int n_in,
                              void* d_out, int out_size, void* d_ws, size_t ws_size,
                              hipStream_t stream) {
    const float* x    = (const float*)d_in[0];
    const float* ew0  = (const float*)d_in[1];
    const float* eb0  = (const float*)d_in[2];
    const float* ew1  = (const float*)d_in[3];
    const float* eb1  = (const float*)d_in[4];
    const float* ew2  = (const float*)d_in[5];
    const float* eb2  = (const float*)d_in[6];
    const float* cb   = (const float*)d_in[7];
    const float* embw = (const float*)d_in[8];
    const float* embb = (const float*)d_in[9];
    const float* dw0  = (const float*)d_in[10];
    const float* db0  = (const float*)d_in[11];
    const float* dw1  = (const float*)d_in[12];
    const float* db1  = (const float*)d_in[13];
    const float* dw2  = (const float*)d_in[14];
    const float* db2  = (const float*)d_in[15];
    const float* muw  = (const float*)d_in[16];
    const float* mub  = (const float*)d_in[17];
    const int*   spk  = (const int*)d_in[18];

    float* zout = (float*)d_out;
    float* cout = zout + (size_t)8192 * 64;
    float* yout = zout + (size_t)2 * 8192 * 64;
    float* din_g = zout + (size_t)8192 * 576;             // tail of yout

    unsigned short* hdec = (unsigned short*)d_ws;

    k_prep<<<dim3(1247), dim3(256), 0, stream>>>(muw, dw1, dw2, ew1, cb, embw);

    k_encoder<<<dim3(4096), dim3(256), 0, stream>>>(
        x, ew0, eb0, eb1, ew2, eb2, zout);

    k_enc_tail<<<dim3(1024), dim3(256), 0, stream>>>(
        zout, cb, embb, spk, cout, din_g);

    k_decoder<<<dim3(4096), dim3(256), 0, stream>>>(din_g, dw0, db0, db1, db2, hdec);

    k_mu_gemm<<<dim3(512), dim3(256), 0, stream>>>(hdec, mub, yout);
}